// Round 9
// baseline (2375.569 us; speedup 1.0000x reference)
//
#include <hip/hip_runtime.h>
#include <cstddef>
#include <cstdint>

constexpr int kSeq = 512;
constexpr int kH   = 256;   // hidden per direction
constexpr int kG   = 1024;  // 4*kH (gates)
constexpr int kE   = 320;   // embed dim
constexpr int kLH  = 512;   // 2*kH
constexpr int kMLP = 512;

typedef _Float16 h2 __attribute__((ext_vector_type(2)));

__device__ __forceinline__ float fexp2f(float x) {
  float r; asm("v_exp_f32 %0, %1" : "=v"(r) : "v"(x)); return r;
}
__device__ __forceinline__ float frcpf(float x) {
  float r; asm("v_rcp_f32 %0, %1" : "=v"(r) : "v"(x)); return r;
}
__device__ __forceinline__ float sigm(float x) {
  return frcpf(1.0f + fexp2f(-1.4426950408889634f * x));
}
__device__ __forceinline__ float tanh_(float x) {
  // tanh(x) = 1 - 2/(1+e^{2x}); e^{2x} = 2^(x*2*log2(e)). inf-safe at both ends.
  return 1.0f - 2.0f * frcpf(1.0f + fexp2f(2.8853900817779268f * x));
}

__device__ __forceinline__ float fdot2(unsigned int w, unsigned int h, float c) {
#if __has_builtin(__builtin_amdgcn_fdot2)
  return __builtin_amdgcn_fdot2(__builtin_bit_cast(h2, w),
                                __builtin_bit_cast(h2, h), c, false);
#else
  const h2 wv = __builtin_bit_cast(h2, w);
  const h2 hv = __builtin_bit_cast(h2, h);
  return c + (float)wv.x * (float)hv.x + (float)wv.y * (float)hv.y;
#endif
}

__device__ __forceinline__ unsigned int packh2(float a, float b) {
  h2 v; v.x = (_Float16)a; v.y = (_Float16)b;
  return __builtin_bit_cast(unsigned int, v);
}

// ---------------- embedding gather ----------------
__global__ void embed_k(const int* __restrict__ wt, const int* __restrict__ pt,
                        const float* __restrict__ we, const float* __restrict__ pe,
                        float* __restrict__ X) {
  const int t = blockIdx.x;
  const int c = threadIdx.x;  // 0..319
  const int w = wt[t];
  const int p = pt[t];
  X[t * kE + c] = (c < 256) ? we[(size_t)w * 256 + c] : pe[p * 64 + (c - 256)];
}

// ---------------- Whh f32 -> packed f16 (both layers, full GPU) ----------------
// Layout: wh16[layer][(d*1024 + row)*128 + c2] = pack(whh[...,2*c2], whh[...,2*c2+1])
__global__ __launch_bounds__(256) void pack_wh_k(
    const float* __restrict__ whh0, const float* __restrict__ whh1,
    unsigned int* __restrict__ wh16) {
  const int idx = blockIdx.x * 256 + threadIdx.x;   // 0 .. 2*262144-1
  const int layer = idx >> 18;                      // 262144 uints per layer
  const int li = idx & 262143;
  const int rowg = li >> 7;                         // d*1024 + row (0..2047)
  const int c2 = li & 127;
  const float* src = (layer ? whh1 : whh0) + (size_t)rowg * kH + c2 * 2;
  wh16[idx] = packh2(src[0], src[1]);
}

// ---------------- generic f32 "NT" GEMM ----------------
template <int BM, int BN, int BK>
__global__ __launch_bounds__(256) void gemm_nt(
    const float* __restrict__ A, int lda,
    const float* __restrict__ B, int ldb,
    const float* __restrict__ b1, const float* __restrict__ b2, float scale,
    float* __restrict__ C, int csm, int csn, int K) {
  const int tid = threadIdx.x;
  const int m0 = blockIdx.y * BM;
  const int n0 = blockIdx.x * BN;
  __shared__ float As[BK][BM];
  __shared__ float Bs[BK][BN];
  const int lm = tid >> 2;
  const int lk = tid & 3;
  const int tx = tid & 15;
  const int ty = tid >> 4;
  float acc[4][4] = {};
  for (int k0 = 0; k0 < K; k0 += BK) {
    const float4 av = *(const float4*)(A + (size_t)(m0 + lm) * lda + k0 + lk * 4);
    const float4 bv = *(const float4*)(B + (size_t)(n0 + lm) * ldb + k0 + lk * 4);
    __syncthreads();
    As[lk * 4 + 0][lm] = av.x; As[lk * 4 + 1][lm] = av.y;
    As[lk * 4 + 2][lm] = av.z; As[lk * 4 + 3][lm] = av.w;
    Bs[lk * 4 + 0][lm] = bv.x; Bs[lk * 4 + 1][lm] = bv.y;
    Bs[lk * 4 + 2][lm] = bv.z; Bs[lk * 4 + 3][lm] = bv.w;
    __syncthreads();
#pragma unroll
    for (int kk = 0; kk < BK; ++kk) {
      const float4 a = *(const float4*)&As[kk][ty * 4];
      const float4 b = *(const float4*)&Bs[kk][tx * 4];
      acc[0][0] = fmaf(a.x, b.x, acc[0][0]);
      acc[0][1] = fmaf(a.x, b.y, acc[0][1]);
      acc[0][2] = fmaf(a.x, b.z, acc[0][2]);
      acc[0][3] = fmaf(a.x, b.w, acc[0][3]);
      acc[1][0] = fmaf(a.y, b.x, acc[1][0]);
      acc[1][1] = fmaf(a.y, b.y, acc[1][1]);
      acc[1][2] = fmaf(a.y, b.z, acc[1][2]);
      acc[1][3] = fmaf(a.y, b.w, acc[1][3]);
      acc[2][0] = fmaf(a.z, b.x, acc[2][0]);
      acc[2][1] = fmaf(a.z, b.y, acc[2][1]);
      acc[2][2] = fmaf(a.z, b.z, acc[2][2]);
      acc[2][3] = fmaf(a.z, b.w, acc[2][3]);
      acc[3][0] = fmaf(a.w, b.x, acc[3][0]);
      acc[3][1] = fmaf(a.w, b.y, acc[3][1]);
      acc[3][2] = fmaf(a.w, b.z, acc[3][2]);
      acc[3][3] = fmaf(a.w, b.w, acc[3][3]);
    }
  }
#pragma unroll
  for (int ii = 0; ii < 4; ++ii) {
#pragma unroll
    for (int jj = 0; jj < 4; ++jj) {
      const int m = m0 + ty * 4 + ii;
      const int n = n0 + tx * 4 + jj;
      float v = acc[ii][jj];
      if (b1) v += b1[n];
      if (b2) v += b2[n];
      C[(size_t)m * csm + (size_t)n * csn] = v * scale;
    }
  }
}

// ---------------- single-block-per-direction LSTM scan, f16, 2 rows/thread ----------------
// 2 blocks (d = blockIdx.x), 512 threads = 8 waves; __launch_bounds__(512, 2)
// (min 2 waves/EU -> 256-reg cap). Thread t owns gate rows {t, 512+t}:
//   t<256:  row t   = i-gate of element t,   row 512+t = g-gate  -> kept LOCAL
//   t>=256: row t   = f-gate of element t-256, row 512+t = o-gate -> via gbuf
// Cols 0..191 of both rows: 48 uint4 (192 regs) from pre-packed wh16;
// cols 192..255 in LDS (128 KB). h broadcast as packed half2 from LDS.
__global__ __launch_bounds__(512, 2) void lstm_scan_f16(
    const unsigned int* __restrict__ wh16,  // (2,1024,128) packed f16 pairs
    const float* __restrict__ pre,          // (2, kSeq, kG) pregates
    float* __restrict__ out) {              // (kSeq, kLH); dir d -> cols [d*kH,+kH)
  extern __shared__ __align__(16) char smem[];
  uint4*        wl4  = (uint4*)smem;                           // 8*1024 uint4 = 128KB
  float*        gbuf = (float*)(smem + 131072);                // 512 f32 = 2KB
  unsigned int* hh   = (unsigned int*)(smem + 131072 + 2048);  // 128 uints = 512B

  const int d = blockIdx.x;
  const int t = threadIdx.x;   // 0..511; owns gate rows t and 512+t

  // ---- prologue: load pre-packed f16 weights ----
  uint4 wr[48];                // [0..23] row t cols 0..191, [24..47] row 512+t
  {
    const uint4* w0 = (const uint4*)wh16 + ((size_t)d * kG + t) * 32;
    const uint4* w1 = w0 + 512 * 32;
#pragma unroll
    for (int k = 0; k < 24; ++k) { wr[k] = w0[k]; wr[24 + k] = w1[k]; }
#pragma unroll
    for (int k = 0; k < 8; ++k) {   // cols 192..255 -> LDS
      wl4[k * 1024 + t]       = w0[24 + k];
      wl4[k * 1024 + 512 + t] = w1[24 + k];
    }
  }
  if (t < 128) hh[t] = 0u;     // h(-1) = 0
  __syncthreads();

  float c = 0.0f;
  const uint4* hh4 = (const uint4*)hh;   // 32 chunks of 4 half2 (8 cols each)

  // prefetch pregates for u=0
  const float* pp0 = pre + ((size_t)d * kSeq + (d ? kSeq - 1 : 0)) * kG;
  float pgA = pp0[t];
  float pgB = pp0[512 + t];

  for (int u = 0; u < kSeq; ++u) {
    const int ts = d ? (kSeq - 1 - u) : u;
    // issue next step's pregate loads; consumed next iteration
    const int un = (u + 1 < kSeq) ? (u + 1) : u;
    const int tn = d ? (kSeq - 1 - un) : un;
    const float* pn = pre + ((size_t)d * kSeq + tn) * kG;
    const float nA = pn[t];
    const float nB = pn[512 + t];

    float A0 = 0.f, A1 = 0.f, A2 = 0.f, A3 = 0.f;   // row t
    float B0 = 0.f, B1 = 0.f, B2 = 0.f, B3 = 0.f;   // row 512+t
#pragma unroll
    for (int k = 0; k < 24; ++k) {       // cols 0..191 from VGPR weights
      const uint4 hv = hh4[k];           // broadcast LDS read (uniform addr)
      A0 = fdot2(wr[k].x, hv.x, A0);
      A1 = fdot2(wr[k].y, hv.y, A1);
      A2 = fdot2(wr[k].z, hv.z, A2);
      A3 = fdot2(wr[k].w, hv.w, A3);
      B0 = fdot2(wr[24 + k].x, hv.x, B0);
      B1 = fdot2(wr[24 + k].y, hv.y, B1);
      B2 = fdot2(wr[24 + k].z, hv.z, B2);
      B3 = fdot2(wr[24 + k].w, hv.w, B3);
    }
#pragma unroll
    for (int k = 0; k < 8; ++k) {        // cols 192..255 from LDS weights
      const uint4 hv = hh4[24 + k];
      const uint4 w0 = wl4[k * 1024 + t];
      const uint4 w1 = wl4[k * 1024 + 512 + t];
      A0 = fdot2(w0.x, hv.x, A0);
      A1 = fdot2(w0.y, hv.y, A1);
      A2 = fdot2(w0.z, hv.z, A2);
      A3 = fdot2(w0.w, hv.w, A3);
      B0 = fdot2(w1.x, hv.x, B0);
      B1 = fdot2(w1.y, hv.y, B1);
      B2 = fdot2(w1.z, hv.z, B2);
      B3 = fdot2(w1.w, hv.w, B3);
    }
    const float redA = (A0 + A1) + (A2 + A3) + pgA;
    const float redB = (B0 + B1) + (B2 + B3) + pgB;
    pgA = nA; pgB = nB;

    if (t >= 256) {            // publish f,o gates
      gbuf[t - 256] = redA;    // f of element t-256
      gbuf[t]       = redB;    // o of element t-256
    }
    __syncthreads();   // S1: f,o available

    if (t < kH) {
      const float gi = redA;           // own i-gate
      const float gg = redB;           // own g-gate
      const float gf = gbuf[t];
      const float go = gbuf[256 + t];
      const float iv = sigm(gi), fv = sigm(gf);
      const float gv = tanh_(gg), ov = sigm(go);
      c = fv * c + iv * gv;
      const float h = ov * tanh_(c);
      ((_Float16*)hh)[t] = (_Float16)h;        // quantized h for the recurrence
      out[(size_t)ts * kLH + d * kH + t] = h;  // full-precision h downstream
    }
    __syncthreads();   // S2: hh(u) assembled
  }
}

// ---------------- pair scorer ----------------
__global__ __launch_bounds__(512) void score_k(
    const float* __restrict__ Up, const float* __restrict__ VT,
    const float* __restrict__ wout, const float* __restrict__ bout,
    float* __restrict__ out) {
  const int i = blockIdx.x;
  const int j = threadIdx.x;
  __shared__ float u_sh[kMLP];
  __shared__ float w_sh[kMLP];
  u_sh[j] = Up[(size_t)i * kMLP + j];
  w_sh[j] = wout[j];
  __syncthreads();
  float acc = 0.0f;
#pragma unroll 4
  for (int m = 0; m < kMLP; ++m) {
    const float x = u_sh[m] + VT[(size_t)m * kSeq + j];  // pre-scaled by 2*log2e
    const float th = 1.0f - 2.0f * frcpf(1.0f + fexp2f(x));
    acc = fmaf(th, w_sh[m], acc);
  }
  const float s = acc + bout[0];
  out[(size_t)i * kSeq + j] = (j == i) ? 0.0f : s;
}

extern "C" void kernel_launch(void* const* d_in, const int* in_sizes, int n_in,
                              void* d_out, int out_size, void* d_ws, size_t ws_size,
                              hipStream_t stream) {
  const int*   wt   = (const int*)d_in[0];
  const int*   pt   = (const int*)d_in[1];
  const float* wemb = (const float*)d_in[2];
  const float* pemb = (const float*)d_in[3];
  const float* wih0 = (const float*)d_in[4];
  const float* whh0 = (const float*)d_in[5];
  const float* bih0 = (const float*)d_in[6];
  const float* bhh0 = (const float*)d_in[7];
  const float* wih1 = (const float*)d_in[8];
  const float* whh1 = (const float*)d_in[9];
  const float* bih1 = (const float*)d_in[10];
  const float* bhh1 = (const float*)d_in[11];
  const float* wlin = (const float*)d_in[12];
  const float* blin = (const float*)d_in[13];
  const float* wout = (const float*)d_in[14];
  const float* bout = (const float*)d_in[15];
  float* outp = (float*)d_out;

  float* ws   = (float*)d_ws;
  float* X    = ws;                      // 512*320
  float* PG0  = X + kSeq * kE;           // 2*512*1024
  float* X1   = PG0 + 2 * kSeq * kG;     // 512*512
  float* PG1  = X1 + kSeq * kLH;         // 2*512*1024
  float* LOUT = PG1 + 2 * kSeq * kG;     // 512*512
  float* U    = LOUT + kSeq * kLH;       // 512*512
  float* VT   = U + kSeq * kMLP;         // 512*512
  unsigned int* WH16 = (unsigned int*)(VT + kSeq * kMLP);  // 2 layers * 262144

  const float SC = 2.8853900817779268f;  // 2*log2(e), folds tanh scaling
  const int kScanLds = 131072 + 2048 + 512;  // weights + gbuf + hh

  hipFuncSetAttribute(reinterpret_cast<const void*>(lstm_scan_f16),
                      hipFuncAttributeMaxDynamicSharedMemorySize, kScanLds);

  embed_k<<<kSeq, kE, 0, stream>>>(wt, pt, wemb, pemb, X);
  pack_wh_k<<<2048, 256, 0, stream>>>(whh0, whh1, WH16);

  for (int d = 0; d < 2; ++d) {
    gemm_nt<64, 64, 16><<<dim3(kG / 64, kSeq / 64), 256, 0, stream>>>(
        X, kE, wih0 + (size_t)d * kG * kE, kE,
        bih0 + d * kG, bhh0 + d * kG, 1.0f,
        PG0 + (size_t)d * kSeq * kG, kG, 1, kE);
  }
  lstm_scan_f16<<<2, 512, kScanLds, stream>>>(WH16, PG0, X1);

  for (int d = 0; d < 2; ++d) {
    gemm_nt<64, 64, 16><<<dim3(kG / 64, kSeq / 64), 256, 0, stream>>>(
        X1, kLH, wih1 + (size_t)d * kG * kLH, kLH,
        bih1 + d * kG, bhh1 + d * kG, 1.0f,
        PG1 + (size_t)d * kSeq * kG, kG, 1, kLH);
  }
  lstm_scan_f16<<<2, 512, kScanLds, stream>>>(WH16 + 2 * kG * 128, PG1, LOUT);

  gemm_nt<64, 64, 16><<<dim3(kMLP / 64, kSeq / 64), 256, 0, stream>>>(
      LOUT, kLH, wlin, 2 * kLH, nullptr, nullptr, SC,
      U, kMLP, 1, kLH);
  gemm_nt<64, 64, 16><<<dim3(kMLP / 64, kSeq / 64), 256, 0, stream>>>(
      LOUT, kLH, wlin + kLH, 2 * kLH, blin, nullptr, SC,
      VT, 1, kSeq, kLH);

  score_k<<<kSeq, 512, 0, stream>>>(U, VT, wout, bout, outp);
}

// Round 10
// 1940.215 us; speedup vs baseline: 1.2244x; 1.2244x over previous
//
#include <hip/hip_runtime.h>
#include <cstddef>
#include <cstdint>

constexpr int kSeq = 512;
constexpr int kH   = 256;   // hidden per direction
constexpr int kG   = 1024;  // 4*kH (gates)
constexpr int kE   = 320;   // embed dim
constexpr int kLH  = 512;   // 2*kH
constexpr int kMLP = 512;

typedef _Float16 h2 __attribute__((ext_vector_type(2)));

__device__ __forceinline__ float fexp2f(float x) {
  float r; asm("v_exp_f32 %0, %1" : "=v"(r) : "v"(x)); return r;
}
__device__ __forceinline__ float frcpf(float x) {
  float r; asm("v_rcp_f32 %0, %1" : "=v"(r) : "v"(x)); return r;
}
__device__ __forceinline__ float sigm(float x) {
  return frcpf(1.0f + fexp2f(-1.4426950408889634f * x));
}
__device__ __forceinline__ float tanh_(float x) {
  // tanh(x) = 1 - 2/(1+e^{2x}); e^{2x} = 2^(x*2*log2(e)). inf-safe at both ends.
  return 1.0f - 2.0f * frcpf(1.0f + fexp2f(2.8853900817779268f * x));
}

__device__ __forceinline__ float fdot2(unsigned int w, unsigned int h, float c) {
#if __has_builtin(__builtin_amdgcn_fdot2)
  return __builtin_amdgcn_fdot2(__builtin_bit_cast(h2, w),
                                __builtin_bit_cast(h2, h), c, false);
#else
  const h2 wv = __builtin_bit_cast(h2, w);
  const h2 hv = __builtin_bit_cast(h2, h);
  return c + (float)wv.x * (float)hv.x + (float)wv.y * (float)hv.y;
#endif
}

__device__ __forceinline__ unsigned int packh2(float a, float b) {
  h2 v; v.x = (_Float16)a; v.y = (_Float16)b;
  return __builtin_bit_cast(unsigned int, v);
}

// ---------------- embedding gather ----------------
__global__ void embed_k(const int* __restrict__ wt, const int* __restrict__ pt,
                        const float* __restrict__ we, const float* __restrict__ pe,
                        float* __restrict__ X) {
  const int t = blockIdx.x;
  const int c = threadIdx.x;  // 0..319
  const int w = wt[t];
  const int p = pt[t];
  X[t * kE + c] = (c < 256) ? we[(size_t)w * 256 + c] : pe[p * 64 + (c - 256)];
}

// ---------------- Whh f32 -> packed f16 (both layers, full GPU) ----------------
// wh16[layer*262144 + (d*1024 + row)*128 + c2] = pack(col 2*c2, col 2*c2+1)
__global__ __launch_bounds__(256) void pack_wh_k(
    const float* __restrict__ whh0, const float* __restrict__ whh1,
    unsigned int* __restrict__ wh16) {
  const int idx = blockIdx.x * 256 + threadIdx.x;   // 0 .. 2*262144-1
  const int layer = idx >> 18;
  const int li = idx & 262143;
  const int rowg = li >> 7;                         // d*1024 + row
  const int c2 = li & 127;
  const float* src = (layer ? whh1 : whh0) + (size_t)rowg * kH + c2 * 2;
  wh16[idx] = packh2(src[0], src[1]);
}

// ---------------- generic f32 "NT" GEMM ----------------
template <int BM, int BN, int BK>
__global__ __launch_bounds__(256) void gemm_nt(
    const float* __restrict__ A, int lda,
    const float* __restrict__ B, int ldb,
    const float* __restrict__ b1, const float* __restrict__ b2, float scale,
    float* __restrict__ C, int csm, int csn, int K) {
  const int tid = threadIdx.x;
  const int m0 = blockIdx.y * BM;
  const int n0 = blockIdx.x * BN;
  __shared__ float As[BK][BM];
  __shared__ float Bs[BK][BN];
  const int lm = tid >> 2;
  const int lk = tid & 3;
  const int tx = tid & 15;
  const int ty = tid >> 4;
  float acc[4][4] = {};
  for (int k0 = 0; k0 < K; k0 += BK) {
    const float4 av = *(const float4*)(A + (size_t)(m0 + lm) * lda + k0 + lk * 4);
    const float4 bv = *(const float4*)(B + (size_t)(n0 + lm) * ldb + k0 + lk * 4);
    __syncthreads();
    As[lk * 4 + 0][lm] = av.x; As[lk * 4 + 1][lm] = av.y;
    As[lk * 4 + 2][lm] = av.z; As[lk * 4 + 3][lm] = av.w;
    Bs[lk * 4 + 0][lm] = bv.x; Bs[lk * 4 + 1][lm] = bv.y;
    Bs[lk * 4 + 2][lm] = bv.z; Bs[lk * 4 + 3][lm] = bv.w;
    __syncthreads();
#pragma unroll
    for (int kk = 0; kk < BK; ++kk) {
      const float4 a = *(const float4*)&As[kk][ty * 4];
      const float4 b = *(const float4*)&Bs[kk][tx * 4];
      acc[0][0] = fmaf(a.x, b.x, acc[0][0]);
      acc[0][1] = fmaf(a.x, b.y, acc[0][1]);
      acc[0][2] = fmaf(a.x, b.z, acc[0][2]);
      acc[0][3] = fmaf(a.x, b.w, acc[0][3]);
      acc[1][0] = fmaf(a.y, b.x, acc[1][0]);
      acc[1][1] = fmaf(a.y, b.y, acc[1][1]);
      acc[1][2] = fmaf(a.y, b.z, acc[1][2]);
      acc[1][3] = fmaf(a.y, b.w, acc[1][3]);
      acc[2][0] = fmaf(a.z, b.x, acc[2][0]);
      acc[2][1] = fmaf(a.z, b.y, acc[2][1]);
      acc[2][2] = fmaf(a.z, b.z, acc[2][2]);
      acc[2][3] = fmaf(a.z, b.w, acc[2][3]);
      acc[3][0] = fmaf(a.w, b.x, acc[3][0]);
      acc[3][1] = fmaf(a.w, b.y, acc[3][1]);
      acc[3][2] = fmaf(a.w, b.z, acc[3][2]);
      acc[3][3] = fmaf(a.w, b.w, acc[3][3]);
    }
  }
#pragma unroll
  for (int ii = 0; ii < 4; ++ii) {
#pragma unroll
    for (int jj = 0; jj < 4; ++jj) {
      const int m = m0 + ty * 4 + ii;
      const int n = n0 + tx * 4 + jj;
      float v = acc[ii][jj];
      if (b1) v += b1[n];
      if (b2) v += b2[n];
      C[(size_t)m * csm + (size_t)n * csn] = v * scale;
    }
  }
}

// ---------------- 2-CU-per-direction LSTM scan, all-VGPR f16 weights ----------------
// 4 blocks: d = bx>>1, slice s = bx&1. Block owns h[s*128, s*128+128): 512 gate
// rows x 256 cols = 256KB f16. 1024 threads, 16 waves, waves_per_eu(4,4) -> hard
// 128-VGPR cap, weights = 64 uints/thread -> guaranteed resident.
// Thread t: wave w=t>>6, lane L=t&63; col-half ch=w&1; local row r=(w>>1)*64+L;
// gate g=r>>7, elem j=r&127; global gate row grow = g*256 + s*128 + j.
// Early waves (ch==s): dot own h-half (local), write pbuf; 2 of them also poll
// the peer's h(u-1) (data-as-flag, fresh slot) and fill hh remote half.
// Late waves (ch==1-s): after S3, dot remote half, gbuf[r]=pbuf[r]+part+pregate.
// Gate threads (t<128): c/h update, publish h (atomic comm store first).
__global__ __launch_bounds__(1024)
__attribute__((amdgpu_waves_per_eu(4, 4)))
void lstm_scan_2cu(
    const unsigned int* __restrict__ wh16,  // (2,1024,128) packed f16 pairs
    const float* __restrict__ pre,          // (2, kSeq, kG) pregates
    float* __restrict__ out,                // (kSeq, kLH)
    float* __restrict__ comm)               // (2, kSeq, kH) f32, pre-zeroed
{
  const int d = blockIdx.x >> 1;
  const int s = blockIdx.x & 1;
  const int t = threadIdx.x;
  const int w = t >> 6;
  const int L = t & 63;
  const int ch = w & 1;                 // col-half
  const int r  = (w >> 1) * 64 + L;     // local row 0..511
  const int g  = r >> 7;                // gate 0..3
  const int j  = r & 127;               // element within slice
  const int grow = g * kH + s * 128 + j;
  const bool early = (ch == s);

  // weights: cols [ch*128, ch*128+128) of global row grow -- 16 uint4 = 64 regs
  uint4 wr[16];
  {
    const uint4* wp = (const uint4*)wh16 + ((size_t)d * kG + grow) * 32 + ch * 16;
#pragma unroll
    for (int k = 0; k < 16; ++k) wr[k] = wp[k];
  }

  __shared__ __align__(16) _Float16 hh16[kH];  // h(u-1) as f16
  __shared__ float pbuf[512];
  __shared__ float gbuf[512];
  if (t < 128) ((h2*)hh16)[t] = h2{(_Float16)0.f, (_Float16)0.f};
  float c = 0.0f;
  __syncthreads();

  const uint4* hh4 = (const uint4*)hh16;   // 32 uint4; this thread uses ch*16..+16
  float* cm = comm + (size_t)d * kSeq * kH;

  // poller mapping: the two lowest early waves; each lane owns one remote word
  const bool isPoller = early && ((w >> 1) < 2);
  const int pe = (w >> 1) * 64 + L;        // 0..127 (valid for pollers)
  const int re = (1 - s) * 128 + pe;       // global element to poll

  for (int u = 0; u < kSeq; ++u) {
    const int ts = d ? (kSeq - 1 - u) : u;
    // late threads: issue pregate load early (resolves during poll window)
    float pg = 0.0f;
    if (!early) pg = pre[((size_t)d * kSeq + ts) * kG + grow];

    if (early) {
      // dot over OWN h-half of h(u-1) (valid since prev S2)
      const uint4* hp = hh4 + ch * 16;
      float a0 = 0.f, a1 = 0.f, a2 = 0.f, a3 = 0.f;
#pragma unroll
      for (int k = 0; k < 16; ++k) {
        const uint4 hv = hp[k];     // wave-uniform LDS broadcast
        a0 = fdot2(wr[k].x, hv.x, a0);
        a1 = fdot2(wr[k].y, hv.y, a1);
        a2 = fdot2(wr[k].z, hv.z, a2);
        a3 = fdot2(wr[k].w, hv.w, a3);
      }
      pbuf[r] = (a0 + a1) + (a2 + a3);
      if (isPoller && u > 0) {
        // poll one remote word of h(u-1); data IS the flag (2-deep pipelined)
        const float* src = &cm[(size_t)(u - 1) * kH + re];
        float a = __hip_atomic_load(src, __ATOMIC_RELAXED, __HIP_MEMORY_SCOPE_AGENT);
        float b = __hip_atomic_load(src, __ATOMIC_RELAXED, __HIP_MEMORY_SCOPE_AGENT);
        while (a == 0.0f) {
          a = b;
          b = __hip_atomic_load(src, __ATOMIC_RELAXED, __HIP_MEMORY_SCOPE_AGENT);
        }
        hh16[re] = (_Float16)(a - 2.0f);
      }
    }
    __syncthreads();   // S3: pbuf + hh remote-half(u-1) ready

    if (!early) {
      const uint4* hp = hh4 + ch * 16;
      float a0 = 0.f, a1 = 0.f, a2 = 0.f, a3 = 0.f;
#pragma unroll
      for (int k = 0; k < 16; ++k) {
        const uint4 hv = hp[k];
        a0 = fdot2(wr[k].x, hv.x, a0);
        a1 = fdot2(wr[k].y, hv.y, a1);
        a2 = fdot2(wr[k].z, hv.z, a2);
        a3 = fdot2(wr[k].w, hv.w, a3);
      }
      gbuf[r] = pbuf[r] + (a0 + a1) + (a2 + a3) + pg;
    }
    __syncthreads();   // S1: gbuf ready

    if (t < 128) {
      const float gi = gbuf[t];
      const float gf = gbuf[128 + t];
      const float gg = gbuf[256 + t];
      const float go = gbuf[384 + t];
      const float iv = sigm(gi), fv = sigm(gf);
      const float gv = tanh_(gg), ov = sigm(go);
      c = fv * c + iv * gv;
      const float h = ov * tanh_(c);
      const int e = s * 128 + t;
      // visibility-critical store first
      __hip_atomic_store(&cm[(size_t)u * kH + e], h + 2.0f,
                         __ATOMIC_RELAXED, __HIP_MEMORY_SCOPE_AGENT);
      hh16[e] = (_Float16)h;
      out[(size_t)ts * kLH + d * kH + e] = h;
    }
    __syncthreads();   // S2: hh own-half(u) ready
  }
}

// ---------------- pair scorer ----------------
__global__ __launch_bounds__(512) void score_k(
    const float* __restrict__ Up, const float* __restrict__ VT,
    const float* __restrict__ wout, const float* __restrict__ bout,
    float* __restrict__ out) {
  const int i = blockIdx.x;
  const int j = threadIdx.x;
  __shared__ float u_sh[kMLP];
  __shared__ float w_sh[kMLP];
  u_sh[j] = Up[(size_t)i * kMLP + j];
  w_sh[j] = wout[j];
  __syncthreads();
  float acc = 0.0f;
#pragma unroll 4
  for (int m = 0; m < kMLP; ++m) {
    const float x = u_sh[m] + VT[(size_t)m * kSeq + j];  // pre-scaled by 2*log2e
    const float th = 1.0f - 2.0f * frcpf(1.0f + fexp2f(x));
    acc = fmaf(th, w_sh[m], acc);
  }
  const float s = acc + bout[0];
  out[(size_t)i * kSeq + j] = (j == i) ? 0.0f : s;
}

extern "C" void kernel_launch(void* const* d_in, const int* in_sizes, int n_in,
                              void* d_out, int out_size, void* d_ws, size_t ws_size,
                              hipStream_t stream) {
  const int*   wt   = (const int*)d_in[0];
  const int*   pt   = (const int*)d_in[1];
  const float* wemb = (const float*)d_in[2];
  const float* pemb = (const float*)d_in[3];
  const float* wih0 = (const float*)d_in[4];
  const float* whh0 = (const float*)d_in[5];
  const float* bih0 = (const float*)d_in[6];
  const float* bhh0 = (const float*)d_in[7];
  const float* wih1 = (const float*)d_in[8];
  const float* whh1 = (const float*)d_in[9];
  const float* bih1 = (const float*)d_in[10];
  const float* bhh1 = (const float*)d_in[11];
  const float* wlin = (const float*)d_in[12];
  const float* blin = (const float*)d_in[13];
  const float* wout = (const float*)d_in[14];
  const float* bout = (const float*)d_in[15];
  float* outp = (float*)d_out;

  float* ws   = (float*)d_ws;
  float* X    = ws;                      // 512*320
  float* PG0  = X + kSeq * kE;           // 2*512*1024
  float* X1   = PG0 + 2 * kSeq * kG;     // 512*512
  float* PG1  = X1 + kSeq * kLH;         // 2*512*1024
  float* LOUT = PG1 + 2 * kSeq * kG;     // 512*512
  float* U    = LOUT + kSeq * kLH;       // 512*512
  float* VT   = U + kSeq * kMLP;         // 512*512
  float* COMM0 = VT + kSeq * kMLP;       // 2*512*256
  float* COMM1 = COMM0 + 2 * kSeq * kH;  // 2*512*256
  unsigned int* WH16 = (unsigned int*)(COMM1 + 2 * kSeq * kH);  // 2*262144

  const float SC = 2.8853900817779268f;  // 2*log2(e), folds tanh scaling

  // zero both layers' comm buffers (data-as-flag; fresh slot per step)
  hipMemsetAsync(COMM0, 0, 2 * 2 * kSeq * kH * sizeof(float), stream);

  embed_k<<<kSeq, kE, 0, stream>>>(wt, pt, wemb, pemb, X);
  pack_wh_k<<<2048, 256, 0, stream>>>(whh0, whh1, WH16);

  for (int d = 0; d < 2; ++d) {
    gemm_nt<64, 64, 16><<<dim3(kG / 64, kSeq / 64), 256, 0, stream>>>(
        X, kE, wih0 + (size_t)d * kG * kE, kE,
        bih0 + d * kG, bhh0 + d * kG, 1.0f,
        PG0 + (size_t)d * kSeq * kG, kG, 1, kE);
  }
  lstm_scan_2cu<<<4, 1024, 0, stream>>>(WH16, PG0, X1, COMM0);

  for (int d = 0; d < 2; ++d) {
    gemm_nt<64, 64, 16><<<dim3(kG / 64, kSeq / 64), 256, 0, stream>>>(
        X1, kLH, wih1 + (size_t)d * kG * kLH, kLH,
        bih1 + d * kG, bhh1 + d * kG, 1.0f,
        PG1 + (size_t)d * kSeq * kG, kG, 1, kLH);
  }
  lstm_scan_2cu<<<4, 1024, 0, stream>>>(WH16 + 2 * kG * 128, PG1, LOUT, COMM1);

  gemm_nt<64, 64, 16><<<dim3(kMLP / 64, kSeq / 64), 256, 0, stream>>>(
      LOUT, kLH, wlin, 2 * kLH, nullptr, nullptr, SC,
      U, kMLP, 1, kLH);
  gemm_nt<64, 64, 16><<<dim3(kMLP / 64, kSeq / 64), 256, 0, stream>>>(
      LOUT, kLH, wlin + kLH, 2 * kLH, blin, nullptr, SC,
      VT, 1, kSeq, kLH);

  score_k<<<kSeq, 512, 0, stream>>>(U, VT, wout, bout, outp);
}

// Round 11
// 1720.905 us; speedup vs baseline: 1.3804x; 1.1274x over previous
//
#include <hip/hip_runtime.h>
#include <cstddef>
#include <cstdint>

constexpr int kSeq = 512;
constexpr int kH   = 256;   // hidden per direction
constexpr int kG   = 1024;  // 4*kH (gates)
constexpr int kE   = 320;   // embed dim
constexpr int kLH  = 512;   // 2*kH
constexpr int kMLP = 512;

typedef _Float16 h2 __attribute__((ext_vector_type(2)));

__device__ __forceinline__ float fexp2f(float x) {
  float r; asm("v_exp_f32 %0, %1" : "=v"(r) : "v"(x)); return r;
}
__device__ __forceinline__ float frcpf(float x) {
  float r; asm("v_rcp_f32 %0, %1" : "=v"(r) : "v"(x)); return r;
}
__device__ __forceinline__ float sigm(float x) {
  return frcpf(1.0f + fexp2f(-1.4426950408889634f * x));
}
__device__ __forceinline__ float tanh_(float x) {
  // tanh(x) = 1 - 2/(1+e^{2x}); e^{2x} = 2^(x*2*log2(e)). inf-safe at both ends.
  return 1.0f - 2.0f * frcpf(1.0f + fexp2f(2.8853900817779268f * x));
}

__device__ __forceinline__ float fdot2(unsigned int w, unsigned int h, float c) {
#if __has_builtin(__builtin_amdgcn_fdot2)
  return __builtin_amdgcn_fdot2(__builtin_bit_cast(h2, w),
                                __builtin_bit_cast(h2, h), c, false);
#else
  const h2 wv = __builtin_bit_cast(h2, w);
  const h2 hv = __builtin_bit_cast(h2, h);
  return c + (float)wv.x * (float)hv.x + (float)wv.y * (float)hv.y;
#endif
}

__device__ __forceinline__ unsigned int packh2(float a, float b) {
  h2 v; v.x = (_Float16)a; v.y = (_Float16)b;
  return __builtin_bit_cast(unsigned int, v);
}

// ---------------- embedding gather ----------------
__global__ void embed_k(const int* __restrict__ wt, const int* __restrict__ pt,
                        const float* __restrict__ we, const float* __restrict__ pe,
                        float* __restrict__ X) {
  const int t = blockIdx.x;
  const int c = threadIdx.x;  // 0..319
  const int w = wt[t];
  const int p = pt[t];
  X[t * kE + c] = (c < 256) ? we[(size_t)w * 256 + c] : pe[p * 64 + (c - 256)];
}

// ---------------- Whh f32 -> packed f16 (both layers, full GPU) ----------------
// wh16[layer*262144 + (d*1024 + row)*128 + c2] = pack(col 2*c2, col 2*c2+1)
__global__ __launch_bounds__(256) void pack_wh_k(
    const float* __restrict__ whh0, const float* __restrict__ whh1,
    unsigned int* __restrict__ wh16) {
  const int idx = blockIdx.x * 256 + threadIdx.x;   // 0 .. 2*262144-1
  const int layer = idx >> 18;
  const int li = idx & 262143;
  const int rowg = li >> 7;                         // d*1024 + row
  const int c2 = li & 127;
  const float* src = (layer ? whh1 : whh0) + (size_t)rowg * kH + c2 * 2;
  wh16[idx] = packh2(src[0], src[1]);
}

// ---------------- generic f32 "NT" GEMM ----------------
template <int BM, int BN, int BK>
__global__ __launch_bounds__(256) void gemm_nt(
    const float* __restrict__ A, int lda,
    const float* __restrict__ B, int ldb,
    const float* __restrict__ b1, const float* __restrict__ b2, float scale,
    float* __restrict__ C, int csm, int csn, int K) {
  const int tid = threadIdx.x;
  const int m0 = blockIdx.y * BM;
  const int n0 = blockIdx.x * BN;
  __shared__ float As[BK][BM];
  __shared__ float Bs[BK][BN];
  const int lm = tid >> 2;
  const int lk = tid & 3;
  const int tx = tid & 15;
  const int ty = tid >> 4;
  float acc[4][4] = {};
  for (int k0 = 0; k0 < K; k0 += BK) {
    const float4 av = *(const float4*)(A + (size_t)(m0 + lm) * lda + k0 + lk * 4);
    const float4 bv = *(const float4*)(B + (size_t)(n0 + lm) * ldb + k0 + lk * 4);
    __syncthreads();
    As[lk * 4 + 0][lm] = av.x; As[lk * 4 + 1][lm] = av.y;
    As[lk * 4 + 2][lm] = av.z; As[lk * 4 + 3][lm] = av.w;
    Bs[lk * 4 + 0][lm] = bv.x; Bs[lk * 4 + 1][lm] = bv.y;
    Bs[lk * 4 + 2][lm] = bv.z; Bs[lk * 4 + 3][lm] = bv.w;
    __syncthreads();
#pragma unroll
    for (int kk = 0; kk < BK; ++kk) {
      const float4 a = *(const float4*)&As[kk][ty * 4];
      const float4 b = *(const float4*)&Bs[kk][tx * 4];
      acc[0][0] = fmaf(a.x, b.x, acc[0][0]);
      acc[0][1] = fmaf(a.x, b.y, acc[0][1]);
      acc[0][2] = fmaf(a.x, b.z, acc[0][2]);
      acc[0][3] = fmaf(a.x, b.w, acc[0][3]);
      acc[1][0] = fmaf(a.y, b.x, acc[1][0]);
      acc[1][1] = fmaf(a.y, b.y, acc[1][1]);
      acc[1][2] = fmaf(a.y, b.z, acc[1][2]);
      acc[1][3] = fmaf(a.y, b.w, acc[1][3]);
      acc[2][0] = fmaf(a.z, b.x, acc[2][0]);
      acc[2][1] = fmaf(a.z, b.y, acc[2][1]);
      acc[2][2] = fmaf(a.z, b.z, acc[2][2]);
      acc[2][3] = fmaf(a.z, b.w, acc[2][3]);
      acc[3][0] = fmaf(a.w, b.x, acc[3][0]);
      acc[3][1] = fmaf(a.w, b.y, acc[3][1]);
      acc[3][2] = fmaf(a.w, b.z, acc[3][2]);
      acc[3][3] = fmaf(a.w, b.w, acc[3][3]);
    }
  }
#pragma unroll
  for (int ii = 0; ii < 4; ++ii) {
#pragma unroll
    for (int jj = 0; jj < 4; ++jj) {
      const int m = m0 + ty * 4 + ii;
      const int n = n0 + tx * 4 + jj;
      float v = acc[ii][jj];
      if (b1) v += b1[n];
      if (b2) v += b2[n];
      C[(size_t)m * csm + (size_t)n * csn] = v * scale;
    }
  }
}

// ---------------- 2-CU-per-direction LSTM scan, poll-overlaps-production ----------------
// 4 blocks: d = bx>>1, slice s = bx&1. Block owns gate rows for h-slice
// [s*128, s*128+128): 512 rows x 256 cols f16. 1024 threads, waves_per_eu(4,4).
// Thread t: wave w=t>>6, lane L=t&63; col-half ch=w&1; local row r=(w>>1)*64+L
// (r = g*128 + j); weights = cols [ch*128,+128) of row grow -> 16 uint4.
// Per step u (2 barriers):
//   Phase A: ALL waves dot their column-half of h(u-1) (hh16 complete from
//            prev step) -> pbuf[ch][r]. Gate threads issue pregate loads first.
//   Sa.
//   Phase B: t<128 (gates): sum partials+pregate, c/h update, atomic-publish
//            h(u) own-half FIRST, write hh16 own-half + out.
//            t in [512,640) (pollers): spin on peer's h(u) -- being produced
//            CONCURRENTLY by the peer's phase B -- fill hh16 remote half.
//   Sb: hh16 = complete h(u).
// The cross-CU visibility latency thus overlaps the peer's own gate compute,
// not our critical path. Data-as-flag: fresh slot/step, h+2.0 never 0 bits.
__global__ __launch_bounds__(1024)
__attribute__((amdgpu_waves_per_eu(4, 4)))
void lstm_scan_2cu(
    const unsigned int* __restrict__ wh16,  // (2,1024,128) packed f16 pairs
    const float* __restrict__ pre,          // (2, kSeq, kG) pregates
    float* __restrict__ out,                // (kSeq, kLH)
    float* __restrict__ comm)               // (2, kSeq, kH) f32, pre-zeroed
{
  const int d = blockIdx.x >> 1;
  const int s = blockIdx.x & 1;
  const int t = threadIdx.x;
  const int w = t >> 6;
  const int L = t & 63;
  const int ch = w & 1;                 // column-half
  const int r  = (w >> 1) * 64 + L;     // local row 0..511  (= g*128 + j)
  const int g  = r >> 7;
  const int j  = r & 127;
  const int grow = g * kH + s * 128 + j;

  uint4 wr[16];                         // cols [ch*128, +128) of row grow
  {
    const uint4* wp = (const uint4*)wh16 + ((size_t)d * kG + grow) * 32 + ch * 16;
#pragma unroll
    for (int k = 0; k < 16; ++k) wr[k] = wp[k];
  }

  __shared__ __align__(16) _Float16 hh16[kH];  // h(u-1), both halves
  __shared__ float pbuf[2][512];
  if (t < 128) ((h2*)hh16)[t] = h2{(_Float16)0.f, (_Float16)0.f};
  float c = 0.0f;
  __syncthreads();

  const uint4* hh4 = (const uint4*)hh16;
  float* cm = comm + (size_t)d * kSeq * kH;
  const bool isGate = (t < 128);
  const bool isPoll = (t >= 512 && t < 640);
  const int re = (1 - s) * 128 + (t - 512);    // element polled (valid if isPoll)

  for (int u = 0; u < kSeq; ++u) {
    const int ts = d ? (kSeq - 1 - u) : u;
    // gate threads: issue this step's 4 pregate loads; resolve under the dot
    float pg0 = 0.f, pg1 = 0.f, pg2 = 0.f, pg3 = 0.f;
    if (isGate) {
      const float* pp = pre + ((size_t)d * kSeq + ts) * kG + s * 128 + t;
      pg0 = pp[0]; pg1 = pp[256]; pg2 = pp[512]; pg3 = pp[768];
    }
    // ---- Phase A: all 16 waves dot their column-half of h(u-1) ----
    {
      const uint4* hp = hh4 + ch * 16;
      float a0 = 0.f, a1 = 0.f, a2 = 0.f, a3 = 0.f;
#pragma unroll
      for (int k = 0; k < 16; ++k) {
        const uint4 hv = hp[k];      // wave-uniform LDS broadcast
        a0 = fdot2(wr[k].x, hv.x, a0);
        a1 = fdot2(wr[k].y, hv.y, a1);
        a2 = fdot2(wr[k].z, hv.z, a2);
        a3 = fdot2(wr[k].w, hv.w, a3);
      }
      pbuf[ch][r] = (a0 + a1) + (a2 + a3);
    }
    __syncthreads();   // Sa: partials complete

    // ---- Phase B: gates (own half) || poll peer's h(u) (remote half) ----
    if (isGate) {
      const float gi = pbuf[0][t]       + pbuf[1][t]       + pg0;
      const float gf = pbuf[0][128 + t] + pbuf[1][128 + t] + pg1;
      const float gg = pbuf[0][256 + t] + pbuf[1][256 + t] + pg2;
      const float go = pbuf[0][384 + t] + pbuf[1][384 + t] + pg3;
      const float iv = sigm(gi), fv = sigm(gf);
      const float gv = tanh_(gg), ov = sigm(go);
      c = fv * c + iv * gv;
      const float h = ov * tanh_(c);
      const int e = s * 128 + t;
      __hip_atomic_store(&cm[(size_t)u * kH + e], h + 2.0f,
                         __ATOMIC_RELAXED, __HIP_MEMORY_SCOPE_AGENT);
      hh16[e] = (_Float16)h;
      out[(size_t)ts * kLH + d * kH + e] = h;
    } else if (isPoll) {
      const float* src = &cm[(size_t)u * kH + re];
      float a = __hip_atomic_load(src, __ATOMIC_RELAXED, __HIP_MEMORY_SCOPE_AGENT);
      float b = __hip_atomic_load(src, __ATOMIC_RELAXED, __HIP_MEMORY_SCOPE_AGENT);
      while (a == 0.0f) {
        a = b;
        b = __hip_atomic_load(src, __ATOMIC_RELAXED, __HIP_MEMORY_SCOPE_AGENT);
      }
      hh16[re] = (_Float16)(a - 2.0f);
    }
    __syncthreads();   // Sb: hh16 = complete h(u)
  }
}

// ---------------- pair scorer ----------------
__global__ __launch_bounds__(512) void score_k(
    const float* __restrict__ Up, const float* __restrict__ VT,
    const float* __restrict__ wout, const float* __restrict__ bout,
    float* __restrict__ out) {
  const int i = blockIdx.x;
  const int j = threadIdx.x;
  __shared__ float u_sh[kMLP];
  __shared__ float w_sh[kMLP];
  u_sh[j] = Up[(size_t)i * kMLP + j];
  w_sh[j] = wout[j];
  __syncthreads();
  float acc = 0.0f;
#pragma unroll 4
  for (int m = 0; m < kMLP; ++m) {
    const float x = u_sh[m] + VT[(size_t)m * kSeq + j];  // pre-scaled by 2*log2e
    const float th = 1.0f - 2.0f * frcpf(1.0f + fexp2f(x));
    acc = fmaf(th, w_sh[m], acc);
  }
  const float s = acc + bout[0];
  out[(size_t)i * kSeq + j] = (j == i) ? 0.0f : s;
}

extern "C" void kernel_launch(void* const* d_in, const int* in_sizes, int n_in,
                              void* d_out, int out_size, void* d_ws, size_t ws_size,
                              hipStream_t stream) {
  const int*   wt   = (const int*)d_in[0];
  const int*   pt   = (const int*)d_in[1];
  const float* wemb = (const float*)d_in[2];
  const float* pemb = (const float*)d_in[3];
  const float* wih0 = (const float*)d_in[4];
  const float* whh0 = (const float*)d_in[5];
  const float* bih0 = (const float*)d_in[6];
  const float* bhh0 = (const float*)d_in[7];
  const float* wih1 = (const float*)d_in[8];
  const float* whh1 = (const float*)d_in[9];
  const float* bih1 = (const float*)d_in[10];
  const float* bhh1 = (const float*)d_in[11];
  const float* wlin = (const float*)d_in[12];
  const float* blin = (const float*)d_in[13];
  const float* wout = (const float*)d_in[14];
  const float* bout = (const float*)d_in[15];
  float* outp = (float*)d_out;

  float* ws   = (float*)d_ws;
  float* X    = ws;                      // 512*320
  float* PG0  = X + kSeq * kE;           // 2*512*1024
  float* X1   = PG0 + 2 * kSeq * kG;     // 512*512
  float* PG1  = X1 + kSeq * kLH;         // 2*512*1024
  float* LOUT = PG1 + 2 * kSeq * kG;     // 512*512
  float* U    = LOUT + kSeq * kLH;       // 512*512
  float* VT   = U + kSeq * kMLP;         // 512*512
  float* COMM0 = VT + kSeq * kMLP;       // 2*512*256
  float* COMM1 = COMM0 + 2 * kSeq * kH;  // 2*512*256
  unsigned int* WH16 = (unsigned int*)(COMM1 + 2 * kSeq * kH);  // 2*262144

  const float SC = 2.8853900817779268f;  // 2*log2(e), folds tanh scaling

  // zero both layers' comm buffers (data-as-flag; fresh slot per step)
  hipMemsetAsync(COMM0, 0, 2 * 2 * kSeq * kH * sizeof(float), stream);

  embed_k<<<kSeq, kE, 0, stream>>>(wt, pt, wemb, pemb, X);
  pack_wh_k<<<2048, 256, 0, stream>>>(whh0, whh1, WH16);

  for (int d = 0; d < 2; ++d) {
    gemm_nt<64, 64, 16><<<dim3(kG / 64, kSeq / 64), 256, 0, stream>>>(
        X, kE, wih0 + (size_t)d * kG * kE, kE,
        bih0 + d * kG, bhh0 + d * kG, 1.0f,
        PG0 + (size_t)d * kSeq * kG, kG, 1, kE);
  }
  lstm_scan_2cu<<<4, 1024, 0, stream>>>(WH16, PG0, X1, COMM0);

  for (int d = 0; d < 2; ++d) {
    gemm_nt<64, 64, 16><<<dim3(kG / 64, kSeq / 64), 256, 0, stream>>>(
        X1, kLH, wih1 + (size_t)d * kG * kLH, kLH,
        bih1 + d * kG, bhh1 + d * kG, 1.0f,
        PG1 + (size_t)d * kSeq * kG, kG, 1, kLH);
  }
  lstm_scan_2cu<<<4, 1024, 0, stream>>>(WH16 + 2 * kG * 128, PG1, LOUT, COMM1);

  gemm_nt<64, 64, 16><<<dim3(kMLP / 64, kSeq / 64), 256, 0, stream>>>(
      LOUT, kLH, wlin, 2 * kLH, nullptr, nullptr, SC,
      U, kMLP, 1, kLH);
  gemm_nt<64, 64, 16><<<dim3(kMLP / 64, kSeq / 64), 256, 0, stream>>>(
      LOUT, kLH, wlin + kLH, 2 * kLH, blin, nullptr, SC,
      VT, 1, kSeq, kLH);

  score_k<<<kSeq, 512, 0, stream>>>(U, VT, wout, bout, outp);
}

// Round 12
// 1627.780 us; speedup vs baseline: 1.4594x; 1.0572x over previous
//
#include <hip/hip_runtime.h>
#include <cstddef>
#include <cstdint>

constexpr int kSeq = 512;
constexpr int kH   = 256;   // hidden per direction
constexpr int kG   = 1024;  // 4*kH (gates)
constexpr int kE   = 320;   // embed dim
constexpr int kLH  = 512;   // 2*kH
constexpr int kMLP = 512;

typedef _Float16 h2 __attribute__((ext_vector_type(2)));

__device__ __forceinline__ float fexp2f(float x) {
  float r; asm("v_exp_f32 %0, %1" : "=v"(r) : "v"(x)); return r;
}
__device__ __forceinline__ float frcpf(float x) {
  float r; asm("v_rcp_f32 %0, %1" : "=v"(r) : "v"(x)); return r;
}
__device__ __forceinline__ float sigm(float x) {
  return frcpf(1.0f + fexp2f(-1.4426950408889634f * x));
}
__device__ __forceinline__ float tanh_(float x) {
  // tanh(x) = 1 - 2/(1+e^{2x}); e^{2x} = 2^(x*2*log2(e)). inf-safe at both ends.
  return 1.0f - 2.0f * frcpf(1.0f + fexp2f(2.8853900817779268f * x));
}

__device__ __forceinline__ float fdot2(unsigned int w, unsigned int h, float c) {
#if __has_builtin(__builtin_amdgcn_fdot2)
  return __builtin_amdgcn_fdot2(__builtin_bit_cast(h2, w),
                                __builtin_bit_cast(h2, h), c, false);
#else
  const h2 wv = __builtin_bit_cast(h2, w);
  const h2 hv = __builtin_bit_cast(h2, h);
  return c + (float)wv.x * (float)hv.x + (float)wv.y * (float)hv.y;
#endif
}

__device__ __forceinline__ unsigned int packh2(float a, float b) {
  h2 v; v.x = (_Float16)a; v.y = (_Float16)b;
  return __builtin_bit_cast(unsigned int, v);
}

// ---------------- embedding gather ----------------
__global__ void embed_k(const int* __restrict__ wt, const int* __restrict__ pt,
                        const float* __restrict__ we, const float* __restrict__ pe,
                        float* __restrict__ X) {
  const int t = blockIdx.x;
  const int c = threadIdx.x;  // 0..319
  const int w = wt[t];
  const int p = pt[t];
  X[t * kE + c] = (c < 256) ? we[(size_t)w * 256 + c] : pe[p * 64 + (c - 256)];
}

// ---------------- Whh f32 -> packed f16 (both layers, full GPU) ----------------
// wh16[layer*262144 + (d*1024 + row)*128 + c2] = pack(col 2*c2, col 2*c2+1)
__global__ __launch_bounds__(256) void pack_wh_k(
    const float* __restrict__ whh0, const float* __restrict__ whh1,
    unsigned int* __restrict__ wh16) {
  const int idx = blockIdx.x * 256 + threadIdx.x;   // 0 .. 2*262144-1
  const int layer = idx >> 18;
  const int li = idx & 262143;
  const int rowg = li >> 7;                         // d*1024 + row
  const int c2 = li & 127;
  const float* src = (layer ? whh1 : whh0) + (size_t)rowg * kH + c2 * 2;
  wh16[idx] = packh2(src[0], src[1]);
}

// ---------------- generic f32 "NT" GEMM ----------------
template <int BM, int BN, int BK>
__global__ __launch_bounds__(256) void gemm_nt(
    const float* __restrict__ A, int lda,
    const float* __restrict__ B, int ldb,
    const float* __restrict__ b1, const float* __restrict__ b2, float scale,
    float* __restrict__ C, int csm, int csn, int K) {
  const int tid = threadIdx.x;
  const int m0 = blockIdx.y * BM;
  const int n0 = blockIdx.x * BN;
  __shared__ float As[BK][BM];
  __shared__ float Bs[BK][BN];
  const int lm = tid >> 2;
  const int lk = tid & 3;
  const int tx = tid & 15;
  const int ty = tid >> 4;
  float acc[4][4] = {};
  for (int k0 = 0; k0 < K; k0 += BK) {
    const float4 av = *(const float4*)(A + (size_t)(m0 + lm) * lda + k0 + lk * 4);
    const float4 bv = *(const float4*)(B + (size_t)(n0 + lm) * ldb + k0 + lk * 4);
    __syncthreads();
    As[lk * 4 + 0][lm] = av.x; As[lk * 4 + 1][lm] = av.y;
    As[lk * 4 + 2][lm] = av.z; As[lk * 4 + 3][lm] = av.w;
    Bs[lk * 4 + 0][lm] = bv.x; Bs[lk * 4 + 1][lm] = bv.y;
    Bs[lk * 4 + 2][lm] = bv.z; Bs[lk * 4 + 3][lm] = bv.w;
    __syncthreads();
#pragma unroll
    for (int kk = 0; kk < BK; ++kk) {
      const float4 a = *(const float4*)&As[kk][ty * 4];
      const float4 b = *(const float4*)&Bs[kk][tx * 4];
      acc[0][0] = fmaf(a.x, b.x, acc[0][0]);
      acc[0][1] = fmaf(a.x, b.y, acc[0][1]);
      acc[0][2] = fmaf(a.x, b.z, acc[0][2]);
      acc[0][3] = fmaf(a.x, b.w, acc[0][3]);
      acc[1][0] = fmaf(a.y, b.x, acc[1][0]);
      acc[1][1] = fmaf(a.y, b.y, acc[1][1]);
      acc[1][2] = fmaf(a.y, b.z, acc[1][2]);
      acc[1][3] = fmaf(a.y, b.w, acc[1][3]);
      acc[2][0] = fmaf(a.z, b.x, acc[2][0]);
      acc[2][1] = fmaf(a.z, b.y, acc[2][1]);
      acc[2][2] = fmaf(a.z, b.z, acc[2][2]);
      acc[2][3] = fmaf(a.z, b.w, acc[2][3]);
      acc[3][0] = fmaf(a.w, b.x, acc[3][0]);
      acc[3][1] = fmaf(a.w, b.y, acc[3][1]);
      acc[3][2] = fmaf(a.w, b.z, acc[3][2]);
      acc[3][3] = fmaf(a.w, b.w, acc[3][3]);
    }
  }
#pragma unroll
  for (int ii = 0; ii < 4; ++ii) {
#pragma unroll
    for (int jj = 0; jj < 4; ++jj) {
      const int m = m0 + ty * 4 + ii;
      const int n = n0 + tx * 4 + jj;
      float v = acc[ii][jj];
      if (b1) v += b1[n];
      if (b2) v += b2[n];
      C[(size_t)m * csm + (size_t)n * csn] = v * scale;
    }
  }
}

// ---------------- 2-CU-per-direction LSTM scan, poll-overlaps-production ----------------
// XCD CO-LOCATION: launch 10 blocks; assuming the m09 round-robin mapping
// (XCD = blockIdx % 8), workers bx in {0,8} (d=0, s=0/1) share XCD0 and
// bx in {1,9} (d=1) share XCD1 -> the h-exchange stays within one XCD's
// coherence neighborhood. If the mapping differs, placement is merely random
// (today's behavior); correctness is carried by agent-scope atomics.
// Per step u (2 barriers):
//   Phase A: ALL 16 waves dot their column-half of h(u-1) -> pbuf[ch][r].
//   Sa.
//   Phase B: t<128: gates, c/h update, atomic-publish h(u) own-half FIRST;
//            t in [512,640): poll peer's h(u) (produced concurrently).
//   Sb: hh16 = complete h(u).
__global__ __launch_bounds__(1024)
__attribute__((amdgpu_waves_per_eu(4, 4)))
void lstm_scan_2cu(
    const unsigned int* __restrict__ wh16,  // (2,1024,128) packed f16 pairs
    const float* __restrict__ pre,          // (2, kSeq, kG) pregates
    float* __restrict__ out,                // (kSeq, kLH)
    float* __restrict__ comm)               // (2, kSeq, kH) f32, pre-zeroed
{
  const int bx = blockIdx.x;
  int d, s;
  if (bx == 0)      { d = 0; s = 0; }
  else if (bx == 1) { d = 1; s = 0; }
  else if (bx == 8) { d = 0; s = 1; }
  else if (bx == 9) { d = 1; s = 1; }
  else return;                         // co-location dummies exit

  const int t = threadIdx.x;
  const int w = t >> 6;
  const int L = t & 63;
  const int ch = w & 1;                 // column-half
  const int r  = (w >> 1) * 64 + L;     // local row 0..511  (= g*128 + j)
  const int g  = r >> 7;
  const int j  = r & 127;
  const int grow = g * kH + s * 128 + j;

  uint4 wr[16];                         // cols [ch*128, +128) of row grow
  {
    const uint4* wp = (const uint4*)wh16 + ((size_t)d * kG + grow) * 32 + ch * 16;
#pragma unroll
    for (int k = 0; k < 16; ++k) wr[k] = wp[k];
  }

  __shared__ __align__(16) _Float16 hh16[kH];  // h(u-1), both halves
  __shared__ float pbuf[2][512];
  if (t < 128) ((h2*)hh16)[t] = h2{(_Float16)0.f, (_Float16)0.f};
  float c = 0.0f;
  __syncthreads();

  const uint4* hh4 = (const uint4*)hh16;
  float* cm = comm + (size_t)d * kSeq * kH;
  const bool isGate = (t < 128);
  const bool isPoll = (t >= 512 && t < 640);
  const int re = (1 - s) * 128 + (t - 512);    // element polled (valid if isPoll)

  for (int u = 0; u < kSeq; ++u) {
    const int ts = d ? (kSeq - 1 - u) : u;
    // gate threads: issue this step's 4 pregate loads; resolve under the dot
    float pg0 = 0.f, pg1 = 0.f, pg2 = 0.f, pg3 = 0.f;
    if (isGate) {
      const float* pp = pre + ((size_t)d * kSeq + ts) * kG + s * 128 + t;
      pg0 = pp[0]; pg1 = pp[256]; pg2 = pp[512]; pg3 = pp[768];
    }
    // ---- Phase A: all 16 waves dot their column-half of h(u-1) ----
    {
      const uint4* hp = hh4 + ch * 16;
      float a0 = 0.f, a1 = 0.f, a2 = 0.f, a3 = 0.f;
#pragma unroll
      for (int k = 0; k < 16; ++k) {
        const uint4 hv = hp[k];      // wave-uniform LDS broadcast
        a0 = fdot2(wr[k].x, hv.x, a0);
        a1 = fdot2(wr[k].y, hv.y, a1);
        a2 = fdot2(wr[k].z, hv.z, a2);
        a3 = fdot2(wr[k].w, hv.w, a3);
      }
      pbuf[ch][r] = (a0 + a1) + (a2 + a3);
    }
    __syncthreads();   // Sa: partials complete

    // ---- Phase B: gates (own half) || poll peer's h(u) (remote half) ----
    if (isGate) {
      const float gi = pbuf[0][t]       + pbuf[1][t]       + pg0;
      const float gf = pbuf[0][128 + t] + pbuf[1][128 + t] + pg1;
      const float gg = pbuf[0][256 + t] + pbuf[1][256 + t] + pg2;
      const float go = pbuf[0][384 + t] + pbuf[1][384 + t] + pg3;
      const float iv = sigm(gi), fv = sigm(gf);
      const float gv = tanh_(gg), ov = sigm(go);
      c = fv * c + iv * gv;
      const float h = ov * tanh_(c);
      const int e = s * 128 + t;
      __hip_atomic_store(&cm[(size_t)u * kH + e], h + 2.0f,
                         __ATOMIC_RELAXED, __HIP_MEMORY_SCOPE_AGENT);
      hh16[e] = (_Float16)h;
      out[(size_t)ts * kLH + d * kH + e] = h;
    } else if (isPoll) {
      const float* src = &cm[(size_t)u * kH + re];
      float a = __hip_atomic_load(src, __ATOMIC_RELAXED, __HIP_MEMORY_SCOPE_AGENT);
      float b = __hip_atomic_load(src, __ATOMIC_RELAXED, __HIP_MEMORY_SCOPE_AGENT);
      while (a == 0.0f) {
        a = b;
        b = __hip_atomic_load(src, __ATOMIC_RELAXED, __HIP_MEMORY_SCOPE_AGENT);
      }
      hh16[re] = (_Float16)(a - 2.0f);
    }
    __syncthreads();   // Sb: hh16 = complete h(u)
  }
}

// ---------------- pair scorer ----------------
__global__ __launch_bounds__(512) void score_k(
    const float* __restrict__ Up, const float* __restrict__ VT,
    const float* __restrict__ wout, const float* __restrict__ bout,
    float* __restrict__ out) {
  const int i = blockIdx.x;
  const int j = threadIdx.x;
  __shared__ float u_sh[kMLP];
  __shared__ float w_sh[kMLP];
  u_sh[j] = Up[(size_t)i * kMLP + j];
  w_sh[j] = wout[j];
  __syncthreads();
  float acc = 0.0f;
#pragma unroll 4
  for (int m = 0; m < kMLP; ++m) {
    const float x = u_sh[m] + VT[(size_t)m * kSeq + j];  // pre-scaled by 2*log2e
    const float th = 1.0f - 2.0f * frcpf(1.0f + fexp2f(x));
    acc = fmaf(th, w_sh[m], acc);
  }
  const float s = acc + bout[0];
  out[(size_t)i * kSeq + j] = (j == i) ? 0.0f : s;
}

extern "C" void kernel_launch(void* const* d_in, const int* in_sizes, int n_in,
                              void* d_out, int out_size, void* d_ws, size_t ws_size,
                              hipStream_t stream) {
  const int*   wt   = (const int*)d_in[0];
  const int*   pt   = (const int*)d_in[1];
  const float* wemb = (const float*)d_in[2];
  const float* pemb = (const float*)d_in[3];
  const float* wih0 = (const float*)d_in[4];
  const float* whh0 = (const float*)d_in[5];
  const float* bih0 = (const float*)d_in[6];
  const float* bhh0 = (const float*)d_in[7];
  const float* wih1 = (const float*)d_in[8];
  const float* whh1 = (const float*)d_in[9];
  const float* bih1 = (const float*)d_in[10];
  const float* bhh1 = (const float*)d_in[11];
  const float* wlin = (const float*)d_in[12];
  const float* blin = (const float*)d_in[13];
  const float* wout = (const float*)d_in[14];
  const float* bout = (const float*)d_in[15];
  float* outp = (float*)d_out;

  float* ws   = (float*)d_ws;
  float* X    = ws;                      // 512*320
  float* PG0  = X + kSeq * kE;           // 2*512*1024
  float* X1   = PG0 + 2 * kSeq * kG;     // 512*512
  float* PG1  = X1 + kSeq * kLH;         // 2*512*1024
  float* LOUT = PG1 + 2 * kSeq * kG;     // 512*512
  float* U    = LOUT + kSeq * kLH;       // 512*512
  float* VT   = U + kSeq * kMLP;         // 512*512
  float* COMM0 = VT + kSeq * kMLP;       // 2*512*256
  float* COMM1 = COMM0 + 2 * kSeq * kH;  // 2*512*256
  unsigned int* WH16 = (unsigned int*)(COMM1 + 2 * kSeq * kH);  // 2*262144

  const float SC = 2.8853900817779268f;  // 2*log2(e), folds tanh scaling

  // zero both layers' comm buffers (data-as-flag; fresh slot per step)
  hipMemsetAsync(COMM0, 0, 2 * 2 * kSeq * kH * sizeof(float), stream);

  embed_k<<<kSeq, kE, 0, stream>>>(wt, pt, wemb, pemb, X);
  pack_wh_k<<<2048, 256, 0, stream>>>(whh0, whh1, WH16);

  for (int d = 0; d < 2; ++d) {
    gemm_nt<64, 64, 16><<<dim3(kG / 64, kSeq / 64), 256, 0, stream>>>(
        X, kE, wih0 + (size_t)d * kG * kE, kE,
        bih0 + d * kG, bhh0 + d * kG, 1.0f,
        PG0 + (size_t)d * kSeq * kG, kG, 1, kE);
  }
  lstm_scan_2cu<<<10, 1024, 0, stream>>>(WH16, PG0, X1, COMM0);

  for (int d = 0; d < 2; ++d) {
    gemm_nt<64, 64, 16><<<dim3(kG / 64, kSeq / 64), 256, 0, stream>>>(
        X1, kLH, wih1 + (size_t)d * kG * kLH, kLH,
        bih1 + d * kG, bhh1 + d * kG, 1.0f,
        PG1 + (size_t)d * kSeq * kG, kG, 1, kLH);
  }
  lstm_scan_2cu<<<10, 1024, 0, stream>>>(WH16 + 2 * kG * 128, PG1, LOUT, COMM1);

  gemm_nt<64, 64, 16><<<dim3(kMLP / 64, kSeq / 64), 256, 0, stream>>>(
      LOUT, kLH, wlin, 2 * kLH, nullptr, nullptr, SC,
      U, kMLP, 1, kLH);
  gemm_nt<64, 64, 16><<<dim3(kMLP / 64, kSeq / 64), 256, 0, stream>>>(
      LOUT, kLH, wlin + kLH, 2 * kLH, blin, nullptr, SC,
      VT, 1, kSeq, kLH);

  score_k<<<kSeq, 512, 0, stream>>>(U, VT, wout, bout, outp);
}